// Round 11
// baseline (152.452 us; speedup 1.0000x reference)
//
#include <hip/hip_runtime.h>
#include <hip/hip_bf16.h>
#include <math.h>

#define BB 4
#define MM 1024
#define RR 256
#define HH 16
#define DHH 64
#define DD (HH*DHH)   // 1024

typedef __attribute__((ext_vector_type(8))) short short8;   // 8 bf16 (MFMA A/B frag)
typedef __attribute__((ext_vector_type(4))) float f32x4;    // MFMA C/D frag

#if defined(__has_builtin)
#  if __has_builtin(__builtin_amdgcn_exp2f)
#    define EXP2F(x) __builtin_amdgcn_exp2f(x)
#  endif
#endif
#ifndef EXP2F
#  define EXP2F(x) __expf((x) * 0.6931471805599453f)
#endif

// pack two fp32 -> bf16x2 via round-half-up + v_perm (3 VALU total)
static __device__ __forceinline__ unsigned pack_bf16_rh(float a, float b) {
    unsigned ua = __builtin_bit_cast(unsigned, a) + 0x8000u;
    unsigned ub = __builtin_bit_cast(unsigned, b) + 0x8000u;
    return __builtin_amdgcn_perm(ub, ua, 0x07060302u);   // {lo=ua[31:16], hi=ub[31:16]}
}
static __device__ __forceinline__ unsigned short bf_rh(float a) {
    return (unsigned short)((__builtin_bit_cast(unsigned, a) + 0x8000u) >> 16);
}

// ---------------- Kernel A: V (R x d) fp32 -> VT (d x R) bf16 (unchanged) ----------
__global__ __launch_bounds__(256) void prep_kernel(
    const float* __restrict__ Vq, const float* __restrict__ Vk, const float* __restrict__ Vv,
    __hip_bfloat16* __restrict__ VTq, __hip_bfloat16* __restrict__ VTk,
    __hip_bfloat16* __restrict__ VTv)
{
    const int t   = threadIdx.x;
    const int z   = blockIdx.x / 256;
    const int rem = blockIdx.x % 256;
    const int r0  = (rem & 7) * 32;
    const int d0  = (rem >> 3) * 32;
    const float* V = (z == 0) ? Vq : (z == 1) ? Vk : Vv;
    __hip_bfloat16* VT = (z == 0) ? VTq : (z == 1) ? VTk : VTv;

    __shared__ __hip_bfloat16 Ts[32][33];
    {
        const int row = t >> 3;
        const int c4  = (t & 7) * 4;
        float4 f = *(const float4*)&V[(size_t)(r0 + row) * DD + d0 + c4];
        Ts[row][c4 + 0] = __float2bfloat16(f.x);
        Ts[row][c4 + 1] = __float2bfloat16(f.y);
        Ts[row][c4 + 2] = __float2bfloat16(f.z);
        Ts[row][c4 + 3] = __float2bfloat16(f.w);
    }
    __syncthreads();
    {
        const int orow = t >> 3;
        const int oc4  = (t & 7) * 4;
        union { unsigned short u[4]; uint2 v; } pk;
        #pragma unroll
        for (int i = 0; i < 4; ++i) pk.u[i] = *(unsigned short*)&Ts[oc4 + i][orow];
        *(uint2*)&VT[(size_t)(d0 + orow) * RR + r0 + oc4] = pk.v;
    }
}

// ---------------- Kernel B: MFMA projection v5 — barrier-free streaming ----------------
// grid (B*M/128, H/2, 3), block 256 (4 waves). Wave = 32 m x 128 d (2 heads), K=256
// fully unrolled. A and B fragments loaded DIRECTLY from global (A: fp32 P rows,
// lane-shaped; B: bf16 VT rows, L2-resident) — no LDS staging, no __syncthreads in
// the K-loop. Per wave: 128 MFMA : 64 B-loads : 32 A-loads, all latency overlapped
// by compiler vmcnt scheduling. LDS only for the coalesced-store epilogue.
__global__ __launch_bounds__(256) void svd_gemm(
    const float* __restrict__ Pq, const float* __restrict__ Pk, const float* __restrict__ Pv,
    const __hip_bfloat16* __restrict__ VTq, const __hip_bfloat16* __restrict__ VTk,
    const __hip_bfloat16* __restrict__ VTv,
    const float* __restrict__ bq, const float* __restrict__ bk, const float* __restrict__ bv,
    const int* __restrict__ pos_ids,
    __hip_bfloat16* __restrict__ qout, __hip_bfloat16* __restrict__ kout,
    __hip_bfloat16* __restrict__ vTout)
{
    const int which = blockIdx.z;
    const float* P           = (which == 0) ? Pq : (which == 1) ? Pk : Pv;
    const __hip_bfloat16* VT = (which == 0) ? VTq : (which == 1) ? VTk : VTv;
    const float* bias        = (which == 0) ? bq : (which == 1) ? bk : bv;

    const int hg  = blockIdx.y;               // heads hg*2, hg*2+1
    const int bm0 = blockIdx.x * 128;
    const int b   = bm0 >> 10;
    const int m0  = bm0 & 1023;
    const int tid = threadIdx.x;
    const int lane = tid & 63;
    const int w    = tid >> 6;
    const int l15  = lane & 15;
    const int quad = lane >> 4;

    __shared__ alignas(16) short EP[128 * 136];           // epilogue scratch, 34.8 KB

    f32x4 acc[2][8];
    #pragma unroll
    for (int mt = 0; mt < 2; ++mt)
        #pragma unroll
        for (int dt = 0; dt < 8; ++dt) acc[mt][dt] = (f32x4){0.f, 0.f, 0.f, 0.f};

    const float* prow0 = P + (size_t)(bm0 + w * 32 + l15) * RR;
    const float* prow1 = prow0 + 16 * RR;
    const short* vtbase = (const short*)VT + (size_t)hg * 128 * RR;

    #pragma unroll
    for (int ks = 0; ks < 8; ++ks) {
        const int ko = ks * 32 + quad * 8;
        float4 a0lo = *(const float4*)(prow0 + ko);
        float4 a0hi = *(const float4*)(prow0 + ko + 4);
        float4 a1lo = *(const float4*)(prow1 + ko);
        float4 a1hi = *(const float4*)(prow1 + ko + 4);
        union { unsigned u[4]; short8 s; } pa0, pa1;
        pa0.u[0] = pack_bf16_rh(a0lo.x, a0lo.y);
        pa0.u[1] = pack_bf16_rh(a0lo.z, a0lo.w);
        pa0.u[2] = pack_bf16_rh(a0hi.x, a0hi.y);
        pa0.u[3] = pack_bf16_rh(a0hi.z, a0hi.w);
        pa1.u[0] = pack_bf16_rh(a1lo.x, a1lo.y);
        pa1.u[1] = pack_bf16_rh(a1lo.z, a1lo.w);
        pa1.u[2] = pack_bf16_rh(a1hi.x, a1hi.y);
        pa1.u[3] = pack_bf16_rh(a1hi.z, a1hi.w);

        #pragma unroll
        for (int dt = 0; dt < 8; ++dt) {
            short8 bf = *(const short8*)(vtbase + (size_t)(dt * 16 + l15) * RR + ko);
            acc[0][dt] = __builtin_amdgcn_mfma_f32_16x16x32_bf16(pa0.s, bf, acc[0][dt], 0, 0, 0);
            acc[1][dt] = __builtin_amdgcn_mfma_f32_16x16x32_bf16(pa1.s, bf, acc[1][dt], 0, 0, 0);
        }
    }

    // ---- bias ----
    #pragma unroll
    for (int dt = 0; dt < 8; ++dt) {
        float bc = bias[hg * 128 + dt * 16 + l15];
        #pragma unroll
        for (int mt = 0; mt < 2; ++mt)
            #pragma unroll
            for (int r = 0; r < 4; ++r) acc[mt][dt][r] += bc;
    }

    if (which < 2) {
        // ---- RoPE in-register, coalesced store via LDS transpose ----
        __hip_bfloat16* out = (which == 0) ? qout : kout;
        int pm[2][4];
        #pragma unroll
        for (int r = 0; r < 4; ++r) {
            pm[0][r] = pos_ids[bm0 + w * 32 + quad * 4 + r];
            pm[1][r] = pos_ids[bm0 + w * 32 + 16 + quad * 4 + r];
        }
        float cB[2][2][4], sB[2][2][4];                    // [freq-half][mt][r]
        #pragma unroll
        for (int f2 = 0; f2 < 2; ++f2) {
            float invf = __powf(10000.0f, -(float)(f2 * 16 + l15) * (1.0f / 32.0f));
            #pragma unroll
            for (int mt = 0; mt < 2; ++mt)
                #pragma unroll
                for (int r = 0; r < 4; ++r)
                    __sincosf((float)pm[mt][r] * invf, &sB[f2][mt][r], &cB[f2][mt][r]);
        }
        short* Ls = EP;                        // [128 m][136]
        #pragma unroll
        for (int mt = 0; mt < 2; ++mt)
            #pragma unroll
            for (int dt = 0; dt < 8; ++dt) {
                const int f2 = dt & 1;
                #pragma unroll
                for (int r = 0; r < 4; ++r) {
                    float x  = acc[mt][dt][r], xp = acc[mt][dt ^ 2][r];
                    float c = cB[f2][mt][r], s = sB[f2][mt][r];
                    float val = ((dt & 3) < 2) ? (x * c - xp * s) : (xp * s + x * c);
                    Ls[(w * 32 + mt * 16 + quad * 4 + r) * 136 + dt * 16 + l15] = (short)bf_rh(val);
                }
            }
        __syncthreads();
        #pragma unroll
        for (int i = 0; i < 8; ++i) {
            int u   = tid + i * 256;           // 0..2047: 128 m x 2 hh x 8 segs
            int ml  = u >> 4;
            int hh  = (u >> 3) & 1;
            int seg = u & 7;
            *(uint4*)&out[(((size_t)b * HH + hg * 2 + hh) * MM + m0 + ml) * DHH + seg * 8] =
                *(const uint4*)&Ls[ml * 136 + hh * 64 + seg * 8];
        }
    } else {
        // ---- v: transpose 128 d x 128 m -> [b][h][d][m] bf16 ----
        short* Tt = EP;                        // [128 d][136]
        #pragma unroll
        for (int dt = 0; dt < 8; ++dt)
            #pragma unroll
            for (int mt = 0; mt < 2; ++mt) {
                uint2 pk;
                pk.x = pack_bf16_rh(acc[mt][dt][0], acc[mt][dt][1]);
                pk.y = pack_bf16_rh(acc[mt][dt][2], acc[mt][dt][3]);
                *(uint2*)&Tt[(dt * 16 + l15) * 136 + w * 32 + mt * 16 + quad * 4] = pk;
            }
        __syncthreads();
        #pragma unroll
        for (int i = 0; i < 8; ++i) {
            int u   = tid + i * 256;           // 0..2047: 128 d-rows x 16 segs
            int row = u >> 4;
            int seg = u & 15;
            int h   = hg * 2 + (row >> 6);
            int din = row & 63;
            *(uint4*)&vTout[(((size_t)b * HH + h) * DHH + din) * MM + m0 + seg * 8] =
                *(const uint4*)&Tt[row * 136 + seg * 8];
        }
    }
}

// ---------------- Kernel C: flash attention v4 — split-K across waves (unchanged) ----
__global__ __launch_bounds__(256, 4) void attn_kernel(
    const __hip_bfloat16* __restrict__ q, const __hip_bfloat16* __restrict__ k,
    const __hip_bfloat16* __restrict__ vT,
    const int* __restrict__ mask, float* __restrict__ out)
{
    const int bh    = blockIdx.x & 63;
    const int qt    = blockIdx.x >> 6;        // 0..15
    const int b     = bh >> 4;
    const int tid   = threadIdx.x;
    const int lane  = tid & 63;
    const int w     = tid >> 6;
    const int mhalf = w & 1;
    const int khalf = w >> 1;
    const int l15   = lane & 15;
    const int quad  = lane >> 4;
    const int q0    = qt * 64;
    const int koff  = khalf * 64;

    __shared__ alignas(16) __hip_bfloat16 Kt[128][72];    // 18.4 KB (reused for combine)
    __shared__ alignas(16) __hip_bfloat16 Vt[64][136];    // 17.4 KB, permuted n

    const short* kbase = (const short*)k  + (size_t)bh * MM * DHH;
    const short* vbase = (const short*)vT + (size_t)bh * DHH * MM;

    short8 qa[2][2];
    #pragma unroll
    for (int mt = 0; mt < 2; ++mt) {
        const short* qb = (const short*)q +
            ((size_t)bh * MM + q0 + mhalf * 32 + mt * 16 + l15) * DHH + quad * 8;
        qa[mt][0] = *(const short8*)(qb);
        qa[mt][1] = *(const short8*)(qb + 32);
    }

    f32x4 Ot[2][4];
    #pragma unroll
    for (int mt = 0; mt < 2; ++mt)
        #pragma unroll
        for (int dt = 0; dt < 4; ++dt) Ot[mt][dt] = (f32x4){0.f, 0.f, 0.f, 0.f};
    float lsum[2] = {0.f, 0.f};

    const int* maskb = mask + b * MM;
    const int srcbase = (lane & 48) | ((lane & 48) >> 2);
    const float k2 = 0.125f * 1.44269504089f;

    for (int nc = 0; nc < MM / 128; ++nc) {
        const int n0 = nc * 128;
        #pragma unroll
        for (int pass = 0; pass < 4; ++pass) {
            int u   = tid + pass * 256;
            int row = u >> 3;
            int cg  = u & 7;
            *(uint4*)&Kt[row][cg * 8] =
                *(const uint4*)(kbase + (size_t)(n0 + row) * DHH + cg * 8);
        }
        #pragma unroll
        for (int pass = 0; pass < 4; ++pass) {
            int u   = tid + pass * 256;
            int row = u >> 4;
            int c   = u & 15;
            union { uint4 q4; uint2 h2[2]; } vld;
            vld.q4 = *(const uint4*)(vbase + (size_t)row * MM + n0 + c * 8);
            int g  = c >> 3;
            int c6 = c & 7;
            int base0 = g * 64 + (c6 >> 2) * 32 + (c6 & 1) * 16 + ((c6 >> 1) & 1) * 4;
            *(uint2*)&Vt[row][base0]     = vld.h2[0];
            *(uint2*)&Vt[row][base0 + 8] = vld.h2[1];
        }
        __syncthreads();

        unsigned long long bal = __ballot(maskb[n0 + koff + lane] != 0);

        f32x4 S[2][4];
        #pragma unroll
        for (int t = 0; t < 4; ++t) {
            const short* kr = (const short*)&Kt[koff + t * 16 + l15][quad * 8];
            short8 ka0 = *(const short8*)(kr);
            short8 ka1 = *(const short8*)(kr + 32);
            #pragma unroll
            for (int mt = 0; mt < 2; ++mt) {
                f32x4 c = (f32x4){0.f, 0.f, 0.f, 0.f};
                c = __builtin_amdgcn_mfma_f32_16x16x32_bf16(ka0, qa[mt][0], c, 0, 0, 0);
                c = __builtin_amdgcn_mfma_f32_16x16x32_bf16(ka1, qa[mt][1], c, 0, 0, 0);
                S[mt][t] = c;
            }
        }

        #pragma unroll
        for (int t = 0; t < 4; ++t) {
            unsigned bits = (unsigned)(bal >> (t * 16 + quad * 4));
            #pragma unroll
            for (int r = 0; r < 4; ++r) {
                float sb = ((bits >> r) & 1u) ? 0.0f : -1e30f;
                #pragma unroll
                for (int mt = 0; mt < 2; ++mt) {
                    float e = EXP2F(fmaf(S[mt][t][r], k2, sb));
                    lsum[mt] += e;
                    S[mt][t][r] = e;
                }
            }
        }

        short8 pa[2][2];
        #pragma unroll
        for (int mt = 0; mt < 2; ++mt)
            #pragma unroll
            for (int p = 0; p < 2; ++p) {
                union { unsigned u[4]; short8 s; } pk;
                pk.u[0] = pack_bf16_rh(S[mt][2*p][0],   S[mt][2*p][1]);
                pk.u[1] = pack_bf16_rh(S[mt][2*p][2],   S[mt][2*p][3]);
                pk.u[2] = pack_bf16_rh(S[mt][2*p+1][0], S[mt][2*p+1][1]);
                pk.u[3] = pack_bf16_rh(S[mt][2*p+1][2], S[mt][2*p+1][3]);
                pa[mt][p] = pk.s;
            }

        #pragma unroll
        for (int p = 0; p < 2; ++p) {
            #pragma unroll
            for (int dt = 0; dt < 4; ++dt) {
                short8 vb = *(const short8*)&Vt[dt * 16 + l15][koff + p * 32 + quad * 8];
                #pragma unroll
                for (int mt = 0; mt < 2; ++mt)
                    Ot[mt][dt] = __builtin_amdgcn_mfma_f32_16x16x32_bf16(pa[mt][p], vb, Ot[mt][dt], 0, 0, 0);
            }
        }
        __syncthreads();
    }

    // ---- combine the two key-halves (plain add: no-max softmax) ----
    float* C = (float*)&Kt[0][0];
    const int cb = (mhalf * 64 + lane) * 34;
    if (khalf == 1) {
        #pragma unroll
        for (int mt = 0; mt < 2; ++mt) {
            #pragma unroll
            for (int dt = 0; dt < 4; ++dt)
                #pragma unroll
                for (int r = 0; r < 4; ++r)
                    C[cb + mt * 16 + dt * 4 + r] = Ot[mt][dt][r];
            C[cb + 32 + mt] = lsum[mt];
        }
    }
    __syncthreads();
    if (khalf == 0) {
        #pragma unroll
        for (int mt = 0; mt < 2; ++mt) {
            #pragma unroll
            for (int dt = 0; dt < 4; ++dt)
                #pragma unroll
                for (int r = 0; r < 4; ++r)
                    Ot[mt][dt][r] += C[cb + mt * 16 + dt * 4 + r];
            lsum[mt] += C[cb + 32 + mt];
        }
        #pragma unroll
        for (int mt = 0; mt < 2; ++mt) {
            float s = lsum[mt];
            s += __shfl_xor(s, 16, 64);
            s += __shfl_xor(s, 32, 64);
            float inv = 1.0f / s;
            float* ob = out + ((size_t)bh * MM + q0 + mhalf * 32 + mt * 16) * DHH;
            #pragma unroll
            for (int r = 0; r < 4; ++r) {
                float ir = __shfl(inv, srcbase + r, 64);
                #pragma unroll
                for (int dt = 0; dt < 4; ++dt)
                    ob[(quad * 4 + r) * DHH + dt * 16 + l15] = Ot[mt][dt][r] * ir;
            }
        }
    }
}

extern "C" void kernel_launch(void* const* d_in, const int* in_sizes, int n_in,
                              void* d_out, int out_size, void* d_ws, size_t ws_size,
                              hipStream_t stream) {
    const float* Pq = (const float*)d_in[0];
    const float* Pk = (const float*)d_in[1];
    const float* Pv = (const float*)d_in[2];
    const float* Vq = (const float*)d_in[3];
    const float* Vk = (const float*)d_in[4];
    const float* Vv = (const float*)d_in[5];
    const float* bq = (const float*)d_in[6];
    const float* bk = (const float*)d_in[7];
    const float* bv = (const float*)d_in[8];
    const int* mask = (const int*)d_in[9];
    const int* pos  = (const int*)d_in[10];
    float* out = (float*)d_out;

    const size_t qkv_elems = (size_t)BB * HH * MM * DHH;
    __hip_bfloat16* qb  = (__hip_bfloat16*)d_ws;
    __hip_bfloat16* kb  = qb + qkv_elems;
    __hip_bfloat16* vT  = kb + qkv_elems;
    __hip_bfloat16* VTq = vT + qkv_elems;
    __hip_bfloat16* VTk = VTq + (size_t)DD * RR;
    __hip_bfloat16* VTv = VTk + (size_t)DD * RR;

    prep_kernel<<<768, 256, 0, stream>>>(Vq, Vk, Vv, VTq, VTk, VTv);

    dim3 gG(BB * MM / 128, HH / 2, 3);
    svd_gemm<<<gG, 256, 0, stream>>>(Pq, Pk, Pv, VTq, VTk, VTv, bq, bk, bv, pos,
                                     qb, kb, vT);

    attn_kernel<<<BB * HH * (MM / 64), 256, 0, stream>>>(qb, kb, vT, mask, out);
}